// Round 22
// baseline (998.699 us; speedup 1.0000x reference)
//
#include <hip/hip_runtime.h>
#include <cstdint>
#include <cstddef>

#define Bn 128
#define Ln 1024
#define Fn 128
#define Hn 64
#define NGn 256           // 4*H
#define NCn 16
#define IN_DIM (Hn + Fn*Hn)   // 8256
#define NT 1024           // 16 waves: 1 scan + 15 refresh
#define NREF 15
#define RING 64

typedef float    f32x4 __attribute__((ext_vector_type(4)));
typedef float    f32x2 __attribute__((ext_vector_type(2)));
typedef _Float16 f16x8 __attribute__((ext_vector_type(8)));
typedef _Float16 f16x2 __attribute__((ext_vector_type(2)));

union U8 { f16x8 v; f16x2 p[4]; };

// ---- dynamic LDS carve (bytes) ----
#define OFF_AB   0                 // 65536  AB[m][u] f32x2 {sig(gf), sig(gi)*tanh(gc)}
#define OFF_GO   65536             // 32768  GO[m][u] f32 sig(go)
#define OFF_H    98304             // 16384  h16[m][64] f16 state
#define OFF_PK   114688            // 8192   pk[j] = {x, dec}
#define OFF_CN   122880            // 16384  CN ring [64][64] f32
#define OFF_MF   139264            // 1024   m[j] u8
#define OFF_PV   140288            // 2048   pv[j] i16
#define OFF_NX   142336            // 2048   nx[j] i16
#define OFF_RDY  144384            // 1024   cn-ready[j] u8 (scan -> refresh)
#define OFF_DON  145408            // 1024   done[j] u8 (refresh -> scan)
#define OFF_C    146432            // 256
#define OFF_RED  146688            // 1024 (fo[128] in prologue; 16x16 red in head)
#define OFF_LOG  147712            // 64
#define LDS_TOTAL 147776           // <= 163840

__device__ __forceinline__ float fsigm(float x) {
    return __fdividef(1.0f, 1.0f + __expf(-x));
}
__device__ __forceinline__ float ftanh(float x) {
    float e = __expf(2.0f * x);
    return 1.0f - __fdividef(2.0f, e + 1.0f);
}
__device__ __forceinline__ float sigm_slow(float x) { return 1.0f / (1.0f + expf(-x)); }

#if __has_builtin(__builtin_amdgcn_fdot2)
#define DOT2(WP, HP, ACC) __builtin_amdgcn_fdot2((WP), (HP), (ACC), false)
#else
#define DOT2(WP, HP, ACC) fmaf((float)(WP)[0], (float)(HP)[0], \
                               fmaf((float)(WP)[1], (float)(HP)[1], (ACC)))
#endif

// Gw[(m*8 + c)*256 + r] (f16x8) = W_gates[m][r][1+8c .. 8+8c]   (r = gate row; gates i,f,o,c)
// Gwb[m*256 + r] (f32x2)        = { W_gates[m][r][0], b_gates[m][r] }
__global__ __launch_bounds__(256)
void prep_f16(const float* __restrict__ Wg, const float* __restrict__ bg,
              f16x8* __restrict__ Gw, f32x2* __restrict__ Gwb)
{
    const int m = blockIdx.x, r = threadIdx.x;
    const float* src = Wg + ((size_t)m * NGn + r) * 65;
    f32x2 wb; wb[0] = src[0]; wb[1] = bg[m * NGn + r];
    Gwb[((size_t)m << 8) + r] = wb;
#pragma unroll
    for (int c = 0; c < 8; ++c) {
        f16x8 v;
#pragma unroll
        for (int e = 0; e < 8; ++e) v[e] = (_Float16)src[1 + 8 * c + e];
        Gw[((size_t)m << 11) + (c << 8) + r] = v;
    }
}

__global__ __launch_bounds__(NT, 1)
void lstm_pre(const float* __restrict__ X, const int* __restrict__ lengths,
              const f16x8* __restrict__ Gw, const f32x2* __restrict__ Gwb,
              const float* __restrict__ wdec, const float* __restrict__ bdec,
              const float* __restrict__ Wo, const float* __restrict__ bo,
              float* __restrict__ out)
{
    extern __shared__ char smem[];
    float*    AB_s = (float*)(smem + OFF_AB);     // [m*128 + u*2 + {0,1}]
    float*    GO_s = (float*)(smem + OFF_GO);     // [m*64 + u]
    _Float16* h16  = (_Float16*)(smem + OFF_H);
    f32x2*    pk_s = (f32x2*)(smem + OFF_PK);
    float*    CN_s = (float*)(smem + OFF_CN);     // [(j&63)*64 + u]
    unsigned char* mf_s = (unsigned char*)(smem + OFF_MF);
    short*         pv_s = (short*)(smem + OFF_PV);
    short*         nx_s = (short*)(smem + OFF_NX);
    unsigned char* rdy  = (unsigned char*)(smem + OFF_RDY);
    unsigned char* don  = (unsigned char*)(smem + OFF_DON);
    float* c_s = (float*)(smem + OFF_C);
    int*   fo_s = (int*)(smem + OFF_RED);        // prologue only
    float* red_lds   = (float*)(smem + OFF_RED); // head only
    float* logit_lds = (float*)(smem + OFF_LOG);

    const int b   = blockIdx.x;
    const int tid = threadIdx.x;
    const int l   = tid & 63;          // lane == hidden unit
    const int w   = tid >> 6;          // wave: 0 = scan, 1..15 = refresh

    const float* mrow = X + ((size_t)b * 4 + 1) * Ln;
    const float* xrow = X + ((size_t)b * 4 + 2) * Ln;
    const float* drow = X + ((size_t)b * 4 + 3) * Ln;

    int len = lengths[b];
    if (len > Ln) len = Ln;

    // stage wdec/bdec temporarily in the (not-yet-used) AB region
    if (tid < Fn) { AB_s[tid] = wdec[tid]; AB_s[Fn + tid] = bdec[tid]; }
    if (tid < Fn) fo_s[tid] = Ln;
    __syncthreads();
    for (int jj = tid; jj < Ln; jj += NT) {
        const int   m   = (int)mrow[jj];
        const float dec = __expf(-fmaxf(0.0f, fmaf(AB_s[m], drow[jj], AB_s[Fn + m])));
        f32x2 t; t[0] = xrow[jj]; t[1] = dec;
        pk_s[jj] = t;
        mf_s[jj] = (unsigned char)m;
        nx_s[jj] = -1;
        rdy[jj] = 0; don[jj] = 0;
    }
    __syncthreads();
    for (int j0 = tid; j0 < Ln; j0 += NT) {
        const int mm = (int)mf_s[j0];
        short pv = -1;
        for (int k = j0 - 1; k >= 0; --k)
            if ((int)mf_s[k] == mm) { pv = (short)k; break; }
        pv_s[j0] = pv;
        if (j0 < len) atomicMin(&fo_s[mm], j0);
    }
    __syncthreads();
    for (int j0 = tid; j0 < Ln; j0 += NT) {
        const int p = (int)pv_s[j0];
        if (p >= 0) nx_s[p] = (short)j0;
    }
    {
        f16x8 hzv;
#pragma unroll
        for (int e = 0; e < 8; ++e) hzv[e] = (_Float16)0.0f;
        for (int i = tid; i < (Fn * Hn / 8); i += NT) ((f16x8*)h16)[i] = hzv;
    }
    __syncthreads();
    // first-occurrence init: A=0 -> gates = x*wx + b; store post-activations
    for (int e = tid; e < Fn * Hn; e += NT) {
        const int m = e >> 6, u = e & 63;
        const int f0 = fo_s[m];
        if (f0 < len) {
            const float xv = pk_s[f0][0];
            const f32x2* bp = Gwb + ((size_t)m << 8) + u;
            const f32x2 wi = bp[0], wf = bp[64], wo = bp[128], wc = bp[192];
            const float gi = fmaf(xv, wi[0], wi[1]);
            const float gf = fmaf(xv, wf[0], wf[1]);
            const float go = fmaf(xv, wo[0], wo[1]);
            const float gc = fmaf(xv, wc[0], wc[1]);
            AB_s[(m << 7) + (u << 1)]     = fsigm(gf);
            AB_s[(m << 7) + (u << 1) + 1] = fsigm(gi) * ftanh(gc);
            GO_s[(m << 6) + u]            = fsigm(go);
        }
    }
    __syncthreads();

    if (w == 0) {
        // ========== SCAN WAVE: pure affine scan  c = a*c + b ==========
        __builtin_amdgcn_s_setprio(1);
        float cu = 0.0f;
        if (len > 0) {
            const int i1 = (1 < len) ? 1 : len - 1;
            const int i2 = (2 < len) ? 2 : len - 1;
            int m0 = (int)mf_s[0],  m1 = (int)mf_s[i1], m2 = (int)mf_s[i2];
            int pv0 = (int)pv_s[0], pv1 = (int)pv_s[i1], pv2 = (int)pv_s[i2];
            int df0 = 1;
            int df1 = (pv1 < 0) ? 1 : (int)*(volatile unsigned char*)(don + ((pv1 < 0) ? 0 : pv1));
            int df2 = (pv2 < 0) ? 1 : (int)*(volatile unsigned char*)(don + ((pv2 < 0) ? 0 : pv2));
            asm volatile("" ::: "memory");
            f32x2 ab0 = *(const f32x2*)(AB_s + (m0 << 7) + (l << 1));
            f32x2 ab1 = *(const f32x2*)(AB_s + (m1 << 7) + (l << 1));
            f32x2 ab2 = *(const f32x2*)(AB_s + (m2 << 7) + (l << 1));
            for (int j = 0; j < len; ++j) {
                // ---- prefetch slot j+3 ----
                const int j3 = (j + 3 < len) ? j + 3 : len - 1;
                const int m3 = (int)mf_s[j3];
                const int pv3 = (int)pv_s[j3];
                const int pvc = (pv3 < 0) ? 0 : pv3;
                const int dq  = (int)*(volatile unsigned char*)(don + pvc);
                const int df3 = (pv3 < 0) ? 1 : dq;
                // ring guard for slot j+3 (check consume of j3-RING)
                if (j3 >= RING) {
                    if (*(volatile unsigned char*)(don + (j3 - RING)) == 0) {
                        while (*(volatile unsigned char*)(don + (j3 - RING)) == 0)
                            asm volatile("s_sleep 1");
                    }
                }
                asm volatile("" ::: "memory");
                f32x2 ab3 = *(const f32x2*)(AB_s + (m3 << 7) + (l << 1));
                // ---- hazard: recent recurrence whose refresh hasn't landed ----
                if (!df0) {
                    while (*(volatile unsigned char*)(don + pv0) == 0)
                        asm volatile("s_sleep 1");
                    asm volatile("" ::: "memory");
                    ab0 = *(const f32x2*)(AB_s + (m0 << 7) + (l << 1));
                }
                // ---- the scan: one fma ----
                const float cn = fmaf(ab0[0], cu, ab0[1]);
                cu = cn;
                CN_s[((j & (RING - 1)) << 6) + l] = cn;
                asm volatile("" ::: "memory");   // compile-time: CN before rdy
                if (l == 0) *(volatile unsigned char*)(rdy + j) = 1;  // DS in-order
                // ---- rotate ----
                m0 = m1; pv0 = pv1; df0 = df1; ab0 = ab1;
                m1 = m2; pv1 = pv2; df1 = df2; ab1 = ab2;
                m2 = m3; pv2 = pv3; df2 = df3; ab2 = ab3;
            }
        }
        __builtin_amdgcn_s_setprio(0);
        c_s[l] = cu;
    } else {
        // ====== REFRESH WAVES: cross-job W prefetch, 15-way round robin ======
        int q = w - 1;
        f16x8 wreg[32];
        float xv = 0.0f, dc = 0.0f;
        f32x2 wbi, wbf, wbo, wbc;
        int jn_cur = -1;
        if (q < len) {
            const int m = (int)mf_s[q];
            jn_cur = (int)nx_s[q];
            if (jn_cur >= 0) {
#pragma unroll
                for (int g = 0; g < 4; ++g) {
                    const f16x8* wp = Gw + ((size_t)m << 11) + (g << 6) + l;
#pragma unroll
                    for (int c = 0; c < 8; ++c) wreg[g * 8 + c] = wp[c << 8];
                }
                const f32x2 pkn = pk_s[jn_cur];
                xv = pkn[0]; dc = pkn[1];
                const f32x2* bp = Gwb + ((size_t)m << 8) + l;
                wbi = bp[0]; wbf = bp[64]; wbo = bp[128]; wbc = bp[192];
            }
        }
        while (q < len) {
            const int m = (int)mf_s[q];
            while (*(volatile unsigned char*)(rdy + q) == 0)
                asm volatile("s_sleep 1");
            asm volatile("" ::: "memory");
            // h for step q
            const float cnq = CN_s[((q & (RING - 1)) << 6) + l];
            const float gov = GO_s[(m << 6) + l];
            const float hv  = gov * ftanh(cnq);
            h16[(m << 6) + l] = (_Float16)hv;
            asm volatile("" ::: "memory");
            if (jn_cur >= 0) {
                U8 hr[8];
                {
                    const f16x8* hp = (const f16x8*)(h16 + (m << 6));
#pragma unroll
                    for (int c = 0; c < 8; ++c) hr[c].v = hp[c];
                }
                float a0 = 0.f, a1 = 0.f, a2 = 0.f, a3 = 0.f;
#pragma unroll
                for (int c = 0; c < 8; ++c) {
                    U8 w0, w1, w2, w3;
                    w0.v = wreg[c]; w1.v = wreg[8 + c];
                    w2.v = wreg[16 + c]; w3.v = wreg[24 + c];
#pragma unroll
                    for (int e = 0; e < 4; ++e) {
                        a0 = DOT2(w0.p[e], hr[c].p[e], a0);
                        a1 = DOT2(w1.p[e], hr[c].p[e], a1);
                        a2 = DOT2(w2.p[e], hr[c].p[e], a2);
                        a3 = DOT2(w3.p[e], hr[c].p[e], a3);
                    }
                }
                const float gi = fmaf(dc, a0, fmaf(xv, wbi[0], wbi[1]));
                const float gf = fmaf(dc, a1, fmaf(xv, wbf[0], wbf[1]));
                const float go = fmaf(dc, a2, fmaf(xv, wbo[0], wbo[1]));
                const float gc = fmaf(dc, a3, fmaf(xv, wbc[0], wbc[1]));
                AB_s[(m << 7) + (l << 1)]     = fsigm(gf);
                AB_s[(m << 7) + (l << 1) + 1] = fsigm(gi) * ftanh(gc);
                GO_s[(m << 6) + l]            = fsigm(go);
            }
            asm volatile("" ::: "memory");   // compile-time: data before don
            if (l == 0) *(volatile unsigned char*)(don + q) = 1;  // DS in-order
            // ---- prefetch next job's W/params (overlaps next spin) ----
            const int q2 = q + NREF;
            if (q2 < len) {
                const int m2 = (int)mf_s[q2];
                jn_cur = (int)nx_s[q2];
                if (jn_cur >= 0) {
#pragma unroll
                    for (int g = 0; g < 4; ++g) {
                        const f16x8* wp = Gw + ((size_t)m2 << 11) + (g << 6) + l;
#pragma unroll
                        for (int c = 0; c < 8; ++c) wreg[g * 8 + c] = wp[c << 8];
                    }
                    const f32x2 pkn = pk_s[jn_cur];
                    xv = pkn[0]; dc = pkn[1];
                    const f32x2* bp = Gwb + ((size_t)m2 << 8) + l;
                    wbi = bp[0]; wbf = bp[64]; wbo = bp[128]; wbc = bp[192];
                }
            }
            q = q2;
        }
    }
    __syncthreads();

    // ---- output head: logits = W_out @ [c; h.flatten()] + b_out, softmax ----
    float p[NCn];
#pragma unroll
    for (int c = 0; c < NCn; ++c) p[c] = 0.0f;
    for (int i = tid; i < IN_DIM; i += NT) {
        const float fv = (i < Hn) ? c_s[i] : (float)h16[i - Hn];
#pragma unroll
        for (int c = 0; c < NCn; ++c)
            p[c] = fmaf(Wo[(size_t)c * IN_DIM + i], fv, p[c]);
    }
#pragma unroll
    for (int c = 0; c < NCn; ++c) {
        float v = p[c];
#pragma unroll
        for (int off = 32; off > 0; off >>= 1) v += __shfl_down(v, off, 64);
        if (l == 0) red_lds[w * NCn + c] = v;
    }
    __syncthreads();
    if (tid < NCn) {
        float s = bo[tid];
#pragma unroll
        for (int sw = 0; sw < (NT / 64); ++sw) s += red_lds[sw * NCn + tid];
        logit_lds[tid] = s;
    }
    __syncthreads();
    if (tid == 0) {
        float mx = logit_lds[0];
        for (int c = 1; c < NCn; ++c) mx = fmaxf(mx, logit_lds[c]);
        float e[NCn], sm = 0.0f;
        for (int c = 0; c < NCn; ++c) { e[c] = expf(logit_lds[c] - mx); sm += e[c]; }
        const float inv = 1.0f / sm;
        for (int c = 0; c < NCn; ++c) out[(size_t)b * NCn + c] = e[c] * inv;
    }
}

// ---- fallback (no workspace): raw f32 weights each step ----
__global__ __launch_bounds__(256)
void lstm_fallback(const float* __restrict__ X, const int* __restrict__ lengths,
                   const float* __restrict__ Wg, const float* __restrict__ bg,
                   const float* __restrict__ wdec, const float* __restrict__ bdec,
                   const float* __restrict__ Wo, const float* __restrict__ bo,
                   float* __restrict__ out)
{
    __shared__ __align__(16) float h_lds[Fn * Hn];
    __shared__ float c_lds[Hn];
    __shared__ int   m_lds[Ln];
    __shared__ float x_lds[Ln];
    __shared__ float d_lds[Ln];
    __shared__ float wd_lds[Fn], bd_lds[Fn];
    __shared__ float red_lds[4 * NCn];
    __shared__ float logit_lds[NCn];

    const int b   = blockIdx.x;
    const int tid = threadIdx.x;
    const int l   = tid & 63;
    const int w   = tid >> 6;
    const int q   = l & 3;
    const int u   = w * 16 + (l >> 2);

    const float* mrow = X + ((size_t)b * 4 + 1) * Ln;
    const float* xrow = X + ((size_t)b * 4 + 2) * Ln;
    const float* drow = X + ((size_t)b * 4 + 3) * Ln;

    for (int i = tid; i < Fn * Hn; i += 256) h_lds[i] = 0.0f;
    if (tid < Hn) c_lds[tid] = 0.0f;
    if (tid < Fn) { wd_lds[tid] = wdec[tid]; bd_lds[tid] = bdec[tid]; }
    for (int i = tid; i < Ln; i += 256) {
        m_lds[i] = (int)mrow[i];
        x_lds[i] = xrow[i];
        d_lds[i] = drow[i];
    }
    __syncthreads();

    int len = lengths[b];
    if (len > Ln) len = Ln;
    const int g_raw = q * 64 + u;

    for (int j = 0; j < len; ++j) {
        const int   mj = m_lds[j];
        const float xj = x_lds[j];
        const float dj = d_lds[j];
        const float dec = expf(-fmaxf(0.0f, fmaf(wd_lds[mj], dj, bd_lds[mj])));
        const float4* hp = (const float4*)(h_lds + mj * Hn);
        const float* row = Wg + ((size_t)mj * NGn + g_raw) * 65;
        float acc = fmaf(row[0], xj, bg[mj * NGn + g_raw]);
        float a0 = 0.f, a1 = 0.f, a2 = 0.f, a3 = 0.f;
#pragma unroll
        for (int k4 = 0; k4 < 16; ++k4) {
            float4 hv = hp[k4];
            a0 = fmaf(row[1 + 4*k4 + 0], hv.x, a0);
            a1 = fmaf(row[1 + 4*k4 + 1], hv.y, a1);
            a2 = fmaf(row[1 + 4*k4 + 2], hv.z, a2);
            a3 = fmaf(row[1 + 4*k4 + 3], hv.w, a3);
        }
        acc = fmaf(dec, (a0 + a1) + (a2 + a3), acc);
        const int base = l & ~3;
        const float gi = __shfl(acc, base + 0, 64);
        const float gf = __shfl(acc, base + 1, 64);
        const float go = __shfl(acc, base + 2, 64);
        const float gc = __shfl(acc, base + 3, 64);
        __syncthreads();
        const float c_new = fmaf(sigm_slow(gf), c_lds[u], sigm_slow(gi) * tanhf(gc));
        if (q == 0) {
            c_lds[u] = c_new;
            h_lds[mj * Hn + u] = sigm_slow(go) * tanhf(c_new);
        }
        __syncthreads();
    }

    float p[NCn];
#pragma unroll
    for (int c = 0; c < NCn; ++c) p[c] = 0.0f;
    for (int i = tid; i < IN_DIM; i += 256) {
        const float fv = (i < Hn) ? c_lds[i] : h_lds[i - Hn];
#pragma unroll
        for (int c = 0; c < NCn; ++c)
            p[c] = fmaf(Wo[(size_t)c * IN_DIM + i], fv, p[c]);
    }
#pragma unroll
    for (int c = 0; c < NCn; ++c) {
        float v = p[c];
#pragma unroll
        for (int off = 32; off > 0; off >>= 1) v += __shfl_down(v, off, 64);
        if (l == 0) red_lds[w * NCn + c] = v;
    }
    __syncthreads();
    if (tid < NCn) {
        logit_lds[tid] = red_lds[tid] + red_lds[NCn + tid] +
                         red_lds[2 * NCn + tid] + red_lds[3 * NCn + tid] + bo[tid];
    }
    __syncthreads();
    if (tid == 0) {
        float mx = logit_lds[0];
        for (int c = 1; c < NCn; ++c) mx = fmaxf(mx, logit_lds[c]);
        float e[NCn], s = 0.0f;
        for (int c = 0; c < NCn; ++c) { e[c] = expf(logit_lds[c] - mx); s += e[c]; }
        const float inv = 1.0f / s;
        for (int c = 0; c < NCn; ++c) out[(size_t)b * NCn + c] = e[c] * inv;
    }
}

extern "C" void kernel_launch(void* const* d_in, const int* in_sizes, int n_in,
                              void* d_out, int out_size, void* d_ws, size_t ws_size,
                              hipStream_t stream)
{
    const float* X      = (const float*)d_in[0];
    const int*   len    = (const int*)  d_in[1];
    const float* Wg     = (const float*)d_in[2];
    const float* bg     = (const float*)d_in[3];
    const float* wdec   = (const float*)d_in[4];
    const float* bdec   = (const float*)d_in[5];
    const float* Wo     = (const float*)d_in[6];
    const float* bo     = (const float*)d_in[7];
    float*       out    = (float*)d_out;

    const size_t gw_bytes  = (size_t)Fn * 2048 * sizeof(f16x8);   // 4,194,304
    const size_t gwb_bytes = (size_t)Fn * 256 * sizeof(f32x2);    // 262,144
    const size_t need      = gw_bytes + gwb_bytes;

    if (ws_size >= need) {
        f16x8* Gw  = (f16x8*)d_ws;
        f32x2* Gwb = (f32x2*)((char*)d_ws + gw_bytes);
        prep_f16<<<Fn, 256, 0, stream>>>(Wg, bg, Gw, Gwb);
        (void)hipFuncSetAttribute((const void*)lstm_pre,
                                  hipFuncAttributeMaxDynamicSharedMemorySize,
                                  LDS_TOTAL);
        lstm_pre<<<Bn, NT, LDS_TOTAL, stream>>>(X, len, Gw, Gwb,
                                                wdec, bdec, Wo, bo, out);
    } else {
        lstm_fallback<<<Bn, 256, 0, stream>>>(X, len, Wg, bg,
                                              wdec, bdec, Wo, bo, out);
    }
}

// Round 23
// 479.924 us; speedup vs baseline: 2.0810x; 2.0810x over previous
//
#include <hip/hip_runtime.h>
#include <cstdint>
#include <cstddef>

#define Bn 128
#define Ln 1024
#define Fn 128
#define Hn 64
#define NGn 256           // 4*H
#define NCn 16
#define IN_DIM (Hn + Fn*Hn)   // 8256
#define NT 1024           // 16 waves: 1 scan + 15 refresh
#define NREF 15
#define RING 64

typedef float    f32x4 __attribute__((ext_vector_type(4)));
typedef float    f32x2 __attribute__((ext_vector_type(2)));
typedef _Float16 f16x8 __attribute__((ext_vector_type(8)));
typedef _Float16 f16x2 __attribute__((ext_vector_type(2)));

union U8 { f16x8 v; f16x2 p[4]; };

// ---- dynamic LDS carve (bytes) ----
#define OFF_AB   0                 // 65536  AB[m][u] f32x2 {sig(gf), sig(gi)*tanh(gc)}
#define OFF_GO   65536             // 32768  GO[m][u] f32 sig(go)
#define OFF_H    98304             // 16384  h16[m][64] f16 state
#define OFF_PK   114688            // 8192   pk[j] = {x, dec}
#define OFF_CN   122880            // 16384  CN ring [64][64] f32
#define OFF_MF   139264            // 1024   m[j] u8
#define OFF_PV   140288            // 2048   pv[j] i16
#define OFF_NX   142336            // 2048   nx[j] i16
#define OFF_RDY  144384            // 1024   cn-ready[j] u8 (scan -> refresh)
#define OFF_DON  145408            // 1024   done[j] u8 (refresh -> scan)
#define OFF_C    146432            // 256
#define OFF_RED  146688            // 1024 (fo[128] in prologue; 16x16 red in head)
#define OFF_LOG  147712            // 64
#define LDS_TOTAL 147776           // <= 163840

__device__ __forceinline__ float fsigm(float x) {
    return __fdividef(1.0f, 1.0f + __expf(-x));
}
__device__ __forceinline__ float ftanh(float x) {
    float e = __expf(2.0f * x);
    return 1.0f - __fdividef(2.0f, e + 1.0f);
}
__device__ __forceinline__ float sigm_slow(float x) { return 1.0f / (1.0f + expf(-x)); }

#if __has_builtin(__builtin_amdgcn_fdot2)
#define DOT2(WP, HP, ACC) __builtin_amdgcn_fdot2((WP), (HP), (ACC), false)
#else
#define DOT2(WP, HP, ACC) fmaf((float)(WP)[0], (float)(HP)[0], \
                               fmaf((float)(WP)[1], (float)(HP)[1], (ACC)))
#endif

// Gw[(m*8 + c)*256 + r] (f16x8) = W_gates[m][r][1+8c .. 8+8c]   (r = gate row; gates i,f,o,c)
// Gwb[m*256 + r] (f32x2)        = { W_gates[m][r][0], b_gates[m][r] }
__global__ __launch_bounds__(256)
void prep_f16(const float* __restrict__ Wg, const float* __restrict__ bg,
              f16x8* __restrict__ Gw, f32x2* __restrict__ Gwb)
{
    const int m = blockIdx.x, r = threadIdx.x;
    const float* src = Wg + ((size_t)m * NGn + r) * 65;
    f32x2 wb; wb[0] = src[0]; wb[1] = bg[m * NGn + r];
    Gwb[((size_t)m << 8) + r] = wb;
#pragma unroll
    for (int c = 0; c < 8; ++c) {
        f16x8 v;
#pragma unroll
        for (int e = 0; e < 8; ++e) v[e] = (_Float16)src[1 + 8 * c + e];
        Gw[((size_t)m << 11) + (c << 8) + r] = v;
    }
}

__global__ __launch_bounds__(NT, 1)
void lstm_pre(const float* __restrict__ X, const int* __restrict__ lengths,
              const f16x8* __restrict__ Gw, const f32x2* __restrict__ Gwb,
              const float* __restrict__ wdec, const float* __restrict__ bdec,
              const float* __restrict__ Wo, const float* __restrict__ bo,
              float* __restrict__ out)
{
    extern __shared__ char smem[];
    float*    AB_s = (float*)(smem + OFF_AB);     // [m*128 + u*2 + {0,1}]
    float*    GO_s = (float*)(smem + OFF_GO);     // [m*64 + u]
    _Float16* h16  = (_Float16*)(smem + OFF_H);
    f32x2*    pk_s = (f32x2*)(smem + OFF_PK);
    float*    CN_s = (float*)(smem + OFF_CN);     // [(j&63)*64 + u]
    unsigned char* mf_s = (unsigned char*)(smem + OFF_MF);
    short*         pv_s = (short*)(smem + OFF_PV);
    short*         nx_s = (short*)(smem + OFF_NX);
    unsigned char* rdy  = (unsigned char*)(smem + OFF_RDY);
    unsigned char* don  = (unsigned char*)(smem + OFF_DON);
    float* c_s = (float*)(smem + OFF_C);
    int*   fo_s = (int*)(smem + OFF_RED);        // prologue only
    float* red_lds   = (float*)(smem + OFF_RED); // head only
    float* logit_lds = (float*)(smem + OFF_LOG);

    const int b   = blockIdx.x;
    const int tid = threadIdx.x;
    const int l   = tid & 63;          // lane == hidden unit
    const int w   = tid >> 6;          // wave: 0 = scan, 1..15 = refresh

    const float* mrow = X + ((size_t)b * 4 + 1) * Ln;
    const float* xrow = X + ((size_t)b * 4 + 2) * Ln;
    const float* drow = X + ((size_t)b * 4 + 3) * Ln;

    int len = lengths[b];
    if (len > Ln) len = Ln;

    // stage wdec/bdec temporarily in the (not-yet-used) AB region
    if (tid < Fn) { AB_s[tid] = wdec[tid]; AB_s[Fn + tid] = bdec[tid]; }
    if (tid < Fn) fo_s[tid] = Ln;
    __syncthreads();
    for (int jj = tid; jj < Ln; jj += NT) {
        const int   m   = (int)mrow[jj];
        const float dec = __expf(-fmaxf(0.0f, fmaf(AB_s[m], drow[jj], AB_s[Fn + m])));
        f32x2 t; t[0] = xrow[jj]; t[1] = dec;
        pk_s[jj] = t;
        mf_s[jj] = (unsigned char)m;
        nx_s[jj] = -1;
        rdy[jj] = 0; don[jj] = 0;
    }
    __syncthreads();
    for (int j0 = tid; j0 < Ln; j0 += NT) {
        const int mm = (int)mf_s[j0];
        short pv = -1;
        for (int k = j0 - 1; k >= 0; --k)
            if ((int)mf_s[k] == mm) { pv = (short)k; break; }
        pv_s[j0] = pv;
        if (j0 < len) atomicMin(&fo_s[mm], j0);
    }
    __syncthreads();
    for (int j0 = tid; j0 < Ln; j0 += NT) {
        const int p = (int)pv_s[j0];
        if (p >= 0) nx_s[p] = (short)j0;
    }
    {
        f16x8 hzv;
#pragma unroll
        for (int e = 0; e < 8; ++e) hzv[e] = (_Float16)0.0f;
        for (int i = tid; i < (Fn * Hn / 8); i += NT) ((f16x8*)h16)[i] = hzv;
    }
    __syncthreads();
    // first-occurrence init: A=0 -> gates = x*wx + b; store post-activations
    for (int e = tid; e < Fn * Hn; e += NT) {
        const int m = e >> 6, u = e & 63;
        const int f0 = fo_s[m];
        if (f0 < len) {
            const float xv = pk_s[f0][0];
            const f32x2* bp = Gwb + ((size_t)m << 8) + u;
            const f32x2 wi = bp[0], wf = bp[64], wo = bp[128], wc = bp[192];
            const float gi = fmaf(xv, wi[0], wi[1]);
            const float gf = fmaf(xv, wf[0], wf[1]);
            const float go = fmaf(xv, wo[0], wo[1]);
            const float gc = fmaf(xv, wc[0], wc[1]);
            AB_s[(m << 7) + (u << 1)]     = fsigm(gf);
            AB_s[(m << 7) + (u << 1) + 1] = fsigm(gi) * ftanh(gc);
            GO_s[(m << 6) + u]            = fsigm(go);
        }
    }
    __syncthreads();

    if (w == 0) {
        // ========== SCAN WAVE: pure affine scan  c = a*c + b ==========
        __builtin_amdgcn_s_setprio(1);
        float cu = 0.0f;
        if (len > 0) {
            const int i1 = (1 < len) ? 1 : len - 1;
            const int i2 = (2 < len) ? 2 : len - 1;
            int m0 = (int)mf_s[0],  m1 = (int)mf_s[i1], m2 = (int)mf_s[i2];
            int pv0 = (int)pv_s[0], pv1 = (int)pv_s[i1], pv2 = (int)pv_s[i2];
            int df0 = 1;
            int df1 = (pv1 < 0) ? 1 : (int)*(volatile unsigned char*)(don + ((pv1 < 0) ? 0 : pv1));
            int df2 = (pv2 < 0) ? 1 : (int)*(volatile unsigned char*)(don + ((pv2 < 0) ? 0 : pv2));
            asm volatile("" ::: "memory");
            f32x2 ab0 = *(const f32x2*)(AB_s + (m0 << 7) + (l << 1));
            f32x2 ab1 = *(const f32x2*)(AB_s + (m1 << 7) + (l << 1));
            f32x2 ab2 = *(const f32x2*)(AB_s + (m2 << 7) + (l << 1));
            for (int j = 0; j < len; ++j) {
                // ---- prefetch slot j+3 ----
                const int j3 = (j + 3 < len) ? j + 3 : len - 1;
                const int m3 = (int)mf_s[j3];
                const int pv3 = (int)pv_s[j3];
                const int pvc = (pv3 < 0) ? 0 : pv3;
                const int dq  = (int)*(volatile unsigned char*)(don + pvc);
                const int df3 = (pv3 < 0) ? 1 : dq;
                // ring guard for slot j+3 (check consume of j3-RING)
                if (j3 >= RING) {
                    if (*(volatile unsigned char*)(don + (j3 - RING)) == 0) {
                        while (*(volatile unsigned char*)(don + (j3 - RING)) == 0)
                            asm volatile("s_sleep 1");
                    }
                }
                asm volatile("" ::: "memory");
                f32x2 ab3 = *(const f32x2*)(AB_s + (m3 << 7) + (l << 1));
                // ---- hazard: recent recurrence whose refresh hasn't landed ----
                if (!df0) {
                    while (*(volatile unsigned char*)(don + pv0) == 0)
                        asm volatile("s_sleep 1");
                    asm volatile("" ::: "memory");
                    ab0 = *(const f32x2*)(AB_s + (m0 << 7) + (l << 1));
                }
                // ---- the scan: one fma ----
                const float cn = fmaf(ab0[0], cu, ab0[1]);
                cu = cn;
                CN_s[((j & (RING - 1)) << 6) + l] = cn;
                asm volatile("" ::: "memory");   // compile-time: CN before rdy
                if (l == 0) *(volatile unsigned char*)(rdy + j) = 1;  // DS in-order
                // ---- rotate ----
                m0 = m1; pv0 = pv1; df0 = df1; ab0 = ab1;
                m1 = m2; pv1 = pv2; df1 = df2; ab1 = ab2;
                m2 = m3; pv2 = pv3; df2 = df3; ab2 = ab3;
            }
        }
        __builtin_amdgcn_s_setprio(0);
        c_s[l] = cu;
    } else {
        // ===== REFRESH WAVES: plain loads AFTER the wait; TLP hides latency ====
        for (int q = w - 1; q < len; q += NREF) {
            const int m  = (int)mf_s[q];
            const int jn = (int)nx_s[q];
            while (*(volatile unsigned char*)(rdy + q) == 0)
                asm volatile("s_sleep 1");
            asm volatile("" ::: "memory");
            // h for step q
            const float cnq = CN_s[((q & (RING - 1)) << 6) + l];
            const float gov = GO_s[(m << 6) + l];
            const float hv  = gov * ftanh(cnq);
            h16[(m << 6) + l] = (_Float16)hv;
            asm volatile("" ::: "memory");
            if (jn >= 0) {
                const f32x2 pkn = pk_s[jn];
                const float xv = pkn[0], dc = pkn[1];
                const f32x2* bp = Gwb + ((size_t)m << 8) + l;
                const f32x2 wbi = bp[0], wbf = bp[64], wbo = bp[128], wbc = bp[192];
                U8 hr[8];
                {
                    const f16x8* hp = (const f16x8*)(h16 + (m << 6));
#pragma unroll
                    for (int c = 0; c < 8; ++c) hr[c].v = hp[c];
                }
                float a0 = 0.f, a1 = 0.f, a2 = 0.f, a3 = 0.f;
#pragma unroll
                for (int g = 0; g < 4; ++g) {
                    const f16x8* wp = Gw + ((size_t)m << 11) + (g << 6) + l;
                    float acc = 0.0f;
#pragma unroll
                    for (int c = 0; c < 8; ++c) {
                        U8 wc; wc.v = wp[c << 8];
#pragma unroll
                        for (int e = 0; e < 4; ++e)
                            acc = DOT2(wc.p[e], hr[c].p[e], acc);
                    }
                    if (g == 0) a0 = acc; else if (g == 1) a1 = acc;
                    else if (g == 2) a2 = acc; else a3 = acc;
                }
                const float gi = fmaf(dc, a0, fmaf(xv, wbi[0], wbi[1]));
                const float gf = fmaf(dc, a1, fmaf(xv, wbf[0], wbf[1]));
                const float go = fmaf(dc, a2, fmaf(xv, wbo[0], wbo[1]));
                const float gc = fmaf(dc, a3, fmaf(xv, wbc[0], wbc[1]));
                AB_s[(m << 7) + (l << 1)]     = fsigm(gf);
                AB_s[(m << 7) + (l << 1) + 1] = fsigm(gi) * ftanh(gc);
                GO_s[(m << 6) + l]            = fsigm(go);
            }
            asm volatile("" ::: "memory");   // compile-time: data before don
            if (l == 0) *(volatile unsigned char*)(don + q) = 1;  // DS in-order
        }
    }
    __syncthreads();

    // ---- output head: logits = W_out @ [c; h.flatten()] + b_out, softmax ----
    float p[NCn];
#pragma unroll
    for (int c = 0; c < NCn; ++c) p[c] = 0.0f;
    for (int i = tid; i < IN_DIM; i += NT) {
        const float fv = (i < Hn) ? c_s[i] : (float)h16[i - Hn];
#pragma unroll
        for (int c = 0; c < NCn; ++c)
            p[c] = fmaf(Wo[(size_t)c * IN_DIM + i], fv, p[c]);
    }
#pragma unroll
    for (int c = 0; c < NCn; ++c) {
        float v = p[c];
#pragma unroll
        for (int off = 32; off > 0; off >>= 1) v += __shfl_down(v, off, 64);
        if (l == 0) red_lds[w * NCn + c] = v;
    }
    __syncthreads();
    if (tid < NCn) {
        float s = bo[tid];
#pragma unroll
        for (int sw = 0; sw < (NT / 64); ++sw) s += red_lds[sw * NCn + tid];
        logit_lds[tid] = s;
    }
    __syncthreads();
    if (tid == 0) {
        float mx = logit_lds[0];
        for (int c = 1; c < NCn; ++c) mx = fmaxf(mx, logit_lds[c]);
        float e[NCn], sm = 0.0f;
        for (int c = 0; c < NCn; ++c) { e[c] = expf(logit_lds[c] - mx); sm += e[c]; }
        const float inv = 1.0f / sm;
        for (int c = 0; c < NCn; ++c) out[(size_t)b * NCn + c] = e[c] * inv;
    }
}

// ---- fallback (no workspace): raw f32 weights each step ----
__global__ __launch_bounds__(256)
void lstm_fallback(const float* __restrict__ X, const int* __restrict__ lengths,
                   const float* __restrict__ Wg, const float* __restrict__ bg,
                   const float* __restrict__ wdec, const float* __restrict__ bdec,
                   const float* __restrict__ Wo, const float* __restrict__ bo,
                   float* __restrict__ out)
{
    __shared__ __align__(16) float h_lds[Fn * Hn];
    __shared__ float c_lds[Hn];
    __shared__ int   m_lds[Ln];
    __shared__ float x_lds[Ln];
    __shared__ float d_lds[Ln];
    __shared__ float wd_lds[Fn], bd_lds[Fn];
    __shared__ float red_lds[4 * NCn];
    __shared__ float logit_lds[NCn];

    const int b   = blockIdx.x;
    const int tid = threadIdx.x;
    const int l   = tid & 63;
    const int w   = tid >> 6;
    const int q   = l & 3;
    const int u   = w * 16 + (l >> 2);

    const float* mrow = X + ((size_t)b * 4 + 1) * Ln;
    const float* xrow = X + ((size_t)b * 4 + 2) * Ln;
    const float* drow = X + ((size_t)b * 4 + 3) * Ln;

    for (int i = tid; i < Fn * Hn; i += 256) h_lds[i] = 0.0f;
    if (tid < Hn) c_lds[tid] = 0.0f;
    if (tid < Fn) { wd_lds[tid] = wdec[tid]; bd_lds[tid] = bdec[tid]; }
    for (int i = tid; i < Ln; i += 256) {
        m_lds[i] = (int)mrow[i];
        x_lds[i] = xrow[i];
        d_lds[i] = drow[i];
    }
    __syncthreads();

    int len = lengths[b];
    if (len > Ln) len = Ln;
    const int g_raw = q * 64 + u;

    for (int j = 0; j < len; ++j) {
        const int   mj = m_lds[j];
        const float xj = x_lds[j];
        const float dj = d_lds[j];
        const float dec = expf(-fmaxf(0.0f, fmaf(wd_lds[mj], dj, bd_lds[mj])));
        const float4* hp = (const float4*)(h_lds + mj * Hn);
        const float* row = Wg + ((size_t)mj * NGn + g_raw) * 65;
        float acc = fmaf(row[0], xj, bg[mj * NGn + g_raw]);
        float a0 = 0.f, a1 = 0.f, a2 = 0.f, a3 = 0.f;
#pragma unroll
        for (int k4 = 0; k4 < 16; ++k4) {
            float4 hv = hp[k4];
            a0 = fmaf(row[1 + 4*k4 + 0], hv.x, a0);
            a1 = fmaf(row[1 + 4*k4 + 1], hv.y, a1);
            a2 = fmaf(row[1 + 4*k4 + 2], hv.z, a2);
            a3 = fmaf(row[1 + 4*k4 + 3], hv.w, a3);
        }
        acc = fmaf(dec, (a0 + a1) + (a2 + a3), acc);
        const int base = l & ~3;
        const float gi = __shfl(acc, base + 0, 64);
        const float gf = __shfl(acc, base + 1, 64);
        const float go = __shfl(acc, base + 2, 64);
        const float gc = __shfl(acc, base + 3, 64);
        __syncthreads();
        const float c_new = fmaf(sigm_slow(gf), c_lds[u], sigm_slow(gi) * tanhf(gc));
        if (q == 0) {
            c_lds[u] = c_new;
            h_lds[mj * Hn + u] = sigm_slow(go) * tanhf(c_new);
        }
        __syncthreads();
    }

    float p[NCn];
#pragma unroll
    for (int c = 0; c < NCn; ++c) p[c] = 0.0f;
    for (int i = tid; i < IN_DIM; i += 256) {
        const float fv = (i < Hn) ? c_lds[i] : h_lds[i - Hn];
#pragma unroll
        for (int c = 0; c < NCn; ++c)
            p[c] = fmaf(Wo[(size_t)c * IN_DIM + i], fv, p[c]);
    }
#pragma unroll
    for (int c = 0; c < NCn; ++c) {
        float v = p[c];
#pragma unroll
        for (int off = 32; off > 0; off >>= 1) v += __shfl_down(v, off, 64);
        if (l == 0) red_lds[w * NCn + c] = v;
    }
    __syncthreads();
    if (tid < NCn) {
        logit_lds[tid] = red_lds[tid] + red_lds[NCn + tid] +
                         red_lds[2 * NCn + tid] + red_lds[3 * NCn + tid] + bo[tid];
    }
    __syncthreads();
    if (tid == 0) {
        float mx = logit_lds[0];
        for (int c = 1; c < NCn; ++c) mx = fmaxf(mx, logit_lds[c]);
        float e[NCn], s = 0.0f;
        for (int c = 0; c < NCn; ++c) { e[c] = expf(logit_lds[c] - mx); s += e[c]; }
        const float inv = 1.0f / s;
        for (int c = 0; c < NCn; ++c) out[(size_t)b * NCn + c] = e[c] * inv;
    }
}

extern "C" void kernel_launch(void* const* d_in, const int* in_sizes, int n_in,
                              void* d_out, int out_size, void* d_ws, size_t ws_size,
                              hipStream_t stream)
{
    const float* X      = (const float*)d_in[0];
    const int*   len    = (const int*)  d_in[1];
    const float* Wg     = (const float*)d_in[2];
    const float* bg     = (const float*)d_in[3];
    const float* wdec   = (const float*)d_in[4];
    const float* bdec   = (const float*)d_in[5];
    const float* Wo     = (const float*)d_in[6];
    const float* bo     = (const float*)d_in[7];
    float*       out    = (float*)d_out;

    const size_t gw_bytes  = (size_t)Fn * 2048 * sizeof(f16x8);   // 4,194,304
    const size_t gwb_bytes = (size_t)Fn * 256 * sizeof(f32x2);    // 262,144
    const size_t need      = gw_bytes + gwb_bytes;

    if (ws_size >= need) {
        f16x8* Gw  = (f16x8*)d_ws;
        f32x2* Gwb = (f32x2*)((char*)d_ws + gw_bytes);
        prep_f16<<<Fn, 256, 0, stream>>>(Wg, bg, Gw, Gwb);
        (void)hipFuncSetAttribute((const void*)lstm_pre,
                                  hipFuncAttributeMaxDynamicSharedMemorySize,
                                  LDS_TOTAL);
        lstm_pre<<<Bn, NT, LDS_TOTAL, stream>>>(X, len, Gw, Gwb,
                                                wdec, bdec, Wo, bo, out);
    } else {
        lstm_fallback<<<Bn, 256, 0, stream>>>(X, len, Wg, bg,
                                              wdec, bdec, Wo, bo, out);
    }
}

// Round 24
// 457.357 us; speedup vs baseline: 2.1836x; 1.0493x over previous
//
#include <hip/hip_runtime.h>
#include <cstdint>
#include <cstddef>

#define Bn 128
#define Ln 1024
#define Fn 128
#define Hn 64
#define NGn 256           // 4*H
#define NCn 16
#define IN_DIM (Hn + Fn*Hn)   // 8256
#define NT 768            // 12 waves: 1 scan + 11 refresh
#define NREF 11
#define RING 64

typedef float    f32x4 __attribute__((ext_vector_type(4)));
typedef float    f32x2 __attribute__((ext_vector_type(2)));
typedef _Float16 f16x8 __attribute__((ext_vector_type(8)));
typedef _Float16 f16x2 __attribute__((ext_vector_type(2)));

union U8 { f16x8 v; f16x2 p[4]; };

// ---- dynamic LDS carve (bytes) ----
#define OFF_AB   0                 // 65536  AB[m][u] f32x2 {sig(gf), sig(gi)*tanh(gc)}
#define OFF_GO   65536             // 32768  GO[m][u] f32 sig(go)
#define OFF_H    98304             // 16384  h16[m][64] f16 state
#define OFF_PK   114688            // 8192   pk[j] = {x, dec}
#define OFF_CN   122880            // 16384  CN ring [64][64] f32
#define OFF_MF   139264            // 1024   m[j] u8
#define OFF_PV   140288            // 2048   pv[j] i16
#define OFF_NX   142336            // 2048   nx[j] i16
#define OFF_RDY  144384            // 1024   cn-ready[j] u8 (scan -> refresh)
#define OFF_DON  145408            // 1024   done[j] u8 (refresh -> scan)
#define OFF_C    146432            // 256
#define OFF_RED  146688            // 1024 (fo[128] in prologue; 12x16 red in head)
#define OFF_LOG  147712            // 64
#define LDS_TOTAL 147776           // <= 163840

__device__ __forceinline__ float fsigm(float x) {
    return __fdividef(1.0f, 1.0f + __expf(-x));
}
__device__ __forceinline__ float ftanh(float x) {
    float e = __expf(2.0f * x);
    return 1.0f - __fdividef(2.0f, e + 1.0f);
}
__device__ __forceinline__ float sigm_slow(float x) { return 1.0f / (1.0f + expf(-x)); }

#if __has_builtin(__builtin_amdgcn_fdot2)
#define DOT2(WP, HP, ACC) __builtin_amdgcn_fdot2((WP), (HP), (ACC), false)
#else
#define DOT2(WP, HP, ACC) fmaf((float)(WP)[0], (float)(HP)[0], \
                               fmaf((float)(WP)[1], (float)(HP)[1], (ACC)))
#endif

// Gw[(m*8 + c)*256 + r] (f16x8) = W_gates[m][r][1+8c .. 8+8c]   (r = gate row; gates i,f,o,c)
// Gwb[m*256 + r] (f32x2)        = { W_gates[m][r][0], b_gates[m][r] }
__global__ __launch_bounds__(256)
void prep_f16(const float* __restrict__ Wg, const float* __restrict__ bg,
              f16x8* __restrict__ Gw, f32x2* __restrict__ Gwb)
{
    const int m = blockIdx.x, r = threadIdx.x;
    const float* src = Wg + ((size_t)m * NGn + r) * 65;
    f32x2 wb; wb[0] = src[0]; wb[1] = bg[m * NGn + r];
    Gwb[((size_t)m << 8) + r] = wb;
#pragma unroll
    for (int c = 0; c < 8; ++c) {
        f16x8 v;
#pragma unroll
        for (int e = 0; e < 8; ++e) v[e] = (_Float16)src[1 + 8 * c + e];
        Gw[((size_t)m << 11) + (c << 8) + r] = v;
    }
}

__global__ __launch_bounds__(NT, 1)
void lstm_pre(const float* __restrict__ X, const int* __restrict__ lengths,
              const f16x8* __restrict__ Gw, const f32x2* __restrict__ Gwb,
              const float* __restrict__ wdec, const float* __restrict__ bdec,
              const float* __restrict__ Wo, const float* __restrict__ bo,
              float* __restrict__ out)
{
    extern __shared__ char smem[];
    float*    AB_s = (float*)(smem + OFF_AB);     // [m*128 + u*2 + {0,1}]
    float*    GO_s = (float*)(smem + OFF_GO);     // [m*64 + u]
    _Float16* h16  = (_Float16*)(smem + OFF_H);
    f32x2*    pk_s = (f32x2*)(smem + OFF_PK);
    float*    CN_s = (float*)(smem + OFF_CN);     // [(j&63)*64 + u]
    unsigned char* mf_s = (unsigned char*)(smem + OFF_MF);
    short*         pv_s = (short*)(smem + OFF_PV);
    short*         nx_s = (short*)(smem + OFF_NX);
    unsigned char* rdy  = (unsigned char*)(smem + OFF_RDY);
    unsigned char* don  = (unsigned char*)(smem + OFF_DON);
    float* c_s = (float*)(smem + OFF_C);
    int*   fo_s = (int*)(smem + OFF_RED);        // prologue only
    float* red_lds   = (float*)(smem + OFF_RED); // head only
    float* logit_lds = (float*)(smem + OFF_LOG);

    const int b   = blockIdx.x;
    const int tid = threadIdx.x;
    const int l   = tid & 63;          // lane == hidden unit
    const int w   = tid >> 6;          // wave: 0 = scan, 1..11 = refresh

    const float* mrow = X + ((size_t)b * 4 + 1) * Ln;
    const float* xrow = X + ((size_t)b * 4 + 2) * Ln;
    const float* drow = X + ((size_t)b * 4 + 3) * Ln;

    int len = lengths[b];
    if (len > Ln) len = Ln;

    // stage wdec/bdec temporarily in the (not-yet-used) AB region
    if (tid < Fn) { AB_s[tid] = wdec[tid]; AB_s[Fn + tid] = bdec[tid]; }
    if (tid < Fn) fo_s[tid] = Ln;
    __syncthreads();
    for (int jj = tid; jj < Ln; jj += NT) {
        const int   m   = (int)mrow[jj];
        const float dec = __expf(-fmaxf(0.0f, fmaf(AB_s[m], drow[jj], AB_s[Fn + m])));
        f32x2 t; t[0] = xrow[jj]; t[1] = dec;
        pk_s[jj] = t;
        mf_s[jj] = (unsigned char)m;
        nx_s[jj] = -1;
        rdy[jj] = 0; don[jj] = 0;
    }
    __syncthreads();
    for (int j0 = tid; j0 < Ln; j0 += NT) {
        const int mm = (int)mf_s[j0];
        short pv = -1;
        for (int k = j0 - 1; k >= 0; --k)
            if ((int)mf_s[k] == mm) { pv = (short)k; break; }
        pv_s[j0] = pv;
        if (j0 < len) atomicMin(&fo_s[mm], j0);
    }
    __syncthreads();
    for (int j0 = tid; j0 < Ln; j0 += NT) {
        const int p = (int)pv_s[j0];
        if (p >= 0) nx_s[p] = (short)j0;
    }
    {
        f16x8 hzv;
#pragma unroll
        for (int e = 0; e < 8; ++e) hzv[e] = (_Float16)0.0f;
        for (int i = tid; i < (Fn * Hn / 8); i += NT) ((f16x8*)h16)[i] = hzv;
    }
    __syncthreads();
    // first-occurrence init: A=0 -> gates = x*wx + b; store post-activations
    for (int e = tid; e < Fn * Hn; e += NT) {
        const int m = e >> 6, u = e & 63;
        const int f0 = fo_s[m];
        if (f0 < len) {
            const float xv = pk_s[f0][0];
            const f32x2* bp = Gwb + ((size_t)m << 8) + u;
            const f32x2 wi = bp[0], wf = bp[64], wo = bp[128], wc = bp[192];
            const float gi = fmaf(xv, wi[0], wi[1]);
            const float gf = fmaf(xv, wf[0], wf[1]);
            const float go = fmaf(xv, wo[0], wo[1]);
            const float gc = fmaf(xv, wc[0], wc[1]);
            AB_s[(m << 7) + (u << 1)]     = fsigm(gf);
            AB_s[(m << 7) + (u << 1) + 1] = fsigm(gi) * ftanh(gc);
            GO_s[(m << 6) + u]            = fsigm(go);
        }
    }
    __syncthreads();

    if (w == 0) {
        // ========== SCAN WAVE: pure affine scan  c = a*c + b ==========
        __builtin_amdgcn_s_setprio(1);
        float cu = 0.0f;
        if (len > 0) {
            const int i1 = (1 < len) ? 1 : len - 1;
            const int i2 = (2 < len) ? 2 : len - 1;
            int m0 = (int)mf_s[0],  m1 = (int)mf_s[i1], m2 = (int)mf_s[i2];
            int pv0 = (int)pv_s[0], pv1 = (int)pv_s[i1], pv2 = (int)pv_s[i2];
            int df0 = 1;
            int df1 = (pv1 < 0) ? 1 : (int)*(volatile unsigned char*)(don + ((pv1 < 0) ? 0 : pv1));
            int df2 = (pv2 < 0) ? 1 : (int)*(volatile unsigned char*)(don + ((pv2 < 0) ? 0 : pv2));
            asm volatile("" ::: "memory");
            f32x2 ab0 = *(const f32x2*)(AB_s + (m0 << 7) + (l << 1));
            f32x2 ab1 = *(const f32x2*)(AB_s + (m1 << 7) + (l << 1));
            f32x2 ab2 = *(const f32x2*)(AB_s + (m2 << 7) + (l << 1));
            for (int j = 0; j < len; ++j) {
                // ---- prefetch slot j+3 ----
                const int j3 = (j + 3 < len) ? j + 3 : len - 1;
                const int m3 = (int)mf_s[j3];
                const int pv3 = (int)pv_s[j3];
                const int pvc = (pv3 < 0) ? 0 : pv3;
                const int dq  = (int)*(volatile unsigned char*)(don + pvc);
                const int df3 = (pv3 < 0) ? 1 : dq;
                // ring guard for slot j+3 (check consume of j3-RING)
                if (j3 >= RING) {
                    if (*(volatile unsigned char*)(don + (j3 - RING)) == 0) {
                        while (*(volatile unsigned char*)(don + (j3 - RING)) == 0)
                            asm volatile("s_sleep 1");
                    }
                }
                asm volatile("" ::: "memory");
                f32x2 ab3 = *(const f32x2*)(AB_s + (m3 << 7) + (l << 1));
                // ---- hazard: recent recurrence whose refresh hasn't landed ----
                if (!df0) {
                    while (*(volatile unsigned char*)(don + pv0) == 0)
                        asm volatile("s_sleep 1");
                    asm volatile("" ::: "memory");
                    ab0 = *(const f32x2*)(AB_s + (m0 << 7) + (l << 1));
                }
                // ---- the scan: one fma ----
                const float cn = fmaf(ab0[0], cu, ab0[1]);
                cu = cn;
                CN_s[((j & (RING - 1)) << 6) + l] = cn;
                asm volatile("" ::: "memory");   // compile-time: CN before rdy
                if (l == 0) *(volatile unsigned char*)(rdy + j) = 1;  // DS in-order
                // ---- rotate ----
                m0 = m1; pv0 = pv1; df0 = df1; ab0 = ab1;
                m1 = m2; pv1 = pv2; df1 = df2; ab1 = ab2;
                m2 = m3; pv2 = pv3; df2 = df3; ab2 = ab3;
            }
        }
        __builtin_amdgcn_s_setprio(0);
        c_s[l] = cu;
    } else {
        // ===== REFRESH WAVES: W preloaded + PINNED before the rdy spin =====
        for (int q = w - 1; q < len; q += NREF) {
            const int m  = (int)mf_s[q];
            const int jn = (int)nx_s[q];
            f16x8 wreg[32];
            float xv = 0.0f, dc = 0.0f;
            f32x2 wbi, wbf, wbo, wbc;
            if (jn >= 0) {
#pragma unroll
                for (int g = 0; g < 4; ++g) {
                    const f16x8* wp = Gw + ((size_t)m << 11) + (g << 6) + l;
#pragma unroll
                    for (int c = 0; c < 8; ++c) wreg[g * 8 + c] = wp[c << 8];
                }
                const f32x2 pkn = pk_s[jn];
                xv = pkn[0]; dc = pkn[1];
                const f32x2* bp = Gwb + ((size_t)m << 8) + l;
                wbi = bp[0]; wbf = bp[64]; wbo = bp[128]; wbc = bp[192];
                // pin: force materialization BEFORE the spin (vmcnt waits here,
                // overlapping time we would spend spinning anyway)
                asm volatile("" : "+v"(wreg[0]), "+v"(wreg[1]), "+v"(wreg[2]),
                                  "+v"(wreg[3]), "+v"(wreg[4]), "+v"(wreg[5]),
                                  "+v"(wreg[6]), "+v"(wreg[7]), "+v"(wreg[8]),
                                  "+v"(wreg[9]), "+v"(wreg[10]), "+v"(wreg[11]),
                                  "+v"(wreg[12]), "+v"(wreg[13]), "+v"(wreg[14]),
                                  "+v"(wreg[15]));
                asm volatile("" : "+v"(wreg[16]), "+v"(wreg[17]), "+v"(wreg[18]),
                                  "+v"(wreg[19]), "+v"(wreg[20]), "+v"(wreg[21]),
                                  "+v"(wreg[22]), "+v"(wreg[23]), "+v"(wreg[24]),
                                  "+v"(wreg[25]), "+v"(wreg[26]), "+v"(wreg[27]),
                                  "+v"(wreg[28]), "+v"(wreg[29]), "+v"(wreg[30]),
                                  "+v"(wreg[31]));
            }
            while (*(volatile unsigned char*)(rdy + q) == 0)
                asm volatile("s_sleep 1");
            asm volatile("" ::: "memory");
            // h for step q
            const float cnq = CN_s[((q & (RING - 1)) << 6) + l];
            const float gov = GO_s[(m << 6) + l];
            const float hv  = gov * ftanh(cnq);
            h16[(m << 6) + l] = (_Float16)hv;
            asm volatile("" ::: "memory");
            if (jn >= 0) {
                U8 hr[8];
                {
                    const f16x8* hp = (const f16x8*)(h16 + (m << 6));
#pragma unroll
                    for (int c = 0; c < 8; ++c) hr[c].v = hp[c];
                }
                float a0 = 0.f, a1 = 0.f, a2 = 0.f, a3 = 0.f;
#pragma unroll
                for (int c = 0; c < 8; ++c) {
                    U8 w0, w1, w2, w3;
                    w0.v = wreg[c]; w1.v = wreg[8 + c];
                    w2.v = wreg[16 + c]; w3.v = wreg[24 + c];
#pragma unroll
                    for (int e = 0; e < 4; ++e) {
                        a0 = DOT2(w0.p[e], hr[c].p[e], a0);
                        a1 = DOT2(w1.p[e], hr[c].p[e], a1);
                        a2 = DOT2(w2.p[e], hr[c].p[e], a2);
                        a3 = DOT2(w3.p[e], hr[c].p[e], a3);
                    }
                }
                const float gi = fmaf(dc, a0, fmaf(xv, wbi[0], wbi[1]));
                const float gf = fmaf(dc, a1, fmaf(xv, wbf[0], wbf[1]));
                const float go = fmaf(dc, a2, fmaf(xv, wbo[0], wbo[1]));
                const float gc = fmaf(dc, a3, fmaf(xv, wbc[0], wbc[1]));
                AB_s[(m << 7) + (l << 1)]     = fsigm(gf);
                AB_s[(m << 7) + (l << 1) + 1] = fsigm(gi) * ftanh(gc);
                GO_s[(m << 6) + l]            = fsigm(go);
            }
            asm volatile("" ::: "memory");   // compile-time: data before don
            if (l == 0) *(volatile unsigned char*)(don + q) = 1;  // DS in-order
        }
    }
    __syncthreads();

    // ---- output head: logits = W_out @ [c; h.flatten()] + b_out, softmax ----
    float p[NCn];
#pragma unroll
    for (int c = 0; c < NCn; ++c) p[c] = 0.0f;
    for (int i = tid; i < IN_DIM; i += NT) {
        const float fv = (i < Hn) ? c_s[i] : (float)h16[i - Hn];
#pragma unroll
        for (int c = 0; c < NCn; ++c)
            p[c] = fmaf(Wo[(size_t)c * IN_DIM + i], fv, p[c]);
    }
#pragma unroll
    for (int c = 0; c < NCn; ++c) {
        float v = p[c];
#pragma unroll
        for (int off = 32; off > 0; off >>= 1) v += __shfl_down(v, off, 64);
        if (l == 0) red_lds[w * NCn + c] = v;
    }
    __syncthreads();
    if (tid < NCn) {
        float s = bo[tid];
#pragma unroll
        for (int sw = 0; sw < (NT / 64); ++sw) s += red_lds[sw * NCn + tid];
        logit_lds[tid] = s;
    }
    __syncthreads();
    if (tid == 0) {
        float mx = logit_lds[0];
        for (int c = 1; c < NCn; ++c) mx = fmaxf(mx, logit_lds[c]);
        float e[NCn], sm = 0.0f;
        for (int c = 0; c < NCn; ++c) { e[c] = expf(logit_lds[c] - mx); sm += e[c]; }
        const float inv = 1.0f / sm;
        for (int c = 0; c < NCn; ++c) out[(size_t)b * NCn + c] = e[c] * inv;
    }
}

// ---- fallback (no workspace): raw f32 weights each step ----
__global__ __launch_bounds__(256)
void lstm_fallback(const float* __restrict__ X, const int* __restrict__ lengths,
                   const float* __restrict__ Wg, const float* __restrict__ bg,
                   const float* __restrict__ wdec, const float* __restrict__ bdec,
                   const float* __restrict__ Wo, const float* __restrict__ bo,
                   float* __restrict__ out)
{
    __shared__ __align__(16) float h_lds[Fn * Hn];
    __shared__ float c_lds[Hn];
    __shared__ int   m_lds[Ln];
    __shared__ float x_lds[Ln];
    __shared__ float d_lds[Ln];
    __shared__ float wd_lds[Fn], bd_lds[Fn];
    __shared__ float red_lds[4 * NCn];
    __shared__ float logit_lds[NCn];

    const int b   = blockIdx.x;
    const int tid = threadIdx.x;
    const int l   = tid & 63;
    const int w   = tid >> 6;
    const int q   = l & 3;
    const int u   = w * 16 + (l >> 2);

    const float* mrow = X + ((size_t)b * 4 + 1) * Ln;
    const float* xrow = X + ((size_t)b * 4 + 2) * Ln;
    const float* drow = X + ((size_t)b * 4 + 3) * Ln;

    for (int i = tid; i < Fn * Hn; i += 256) h_lds[i] = 0.0f;
    if (tid < Hn) c_lds[tid] = 0.0f;
    if (tid < Fn) { wd_lds[tid] = wdec[tid]; bd_lds[tid] = bdec[tid]; }
    for (int i = tid; i < Ln; i += 256) {
        m_lds[i] = (int)mrow[i];
        x_lds[i] = xrow[i];
        d_lds[i] = drow[i];
    }
    __syncthreads();

    int len = lengths[b];
    if (len > Ln) len = Ln;
    const int g_raw = q * 64 + u;

    for (int j = 0; j < len; ++j) {
        const int   mj = m_lds[j];
        const float xj = x_lds[j];
        const float dj = d_lds[j];
        const float dec = expf(-fmaxf(0.0f, fmaf(wd_lds[mj], dj, bd_lds[mj])));
        const float4* hp = (const float4*)(h_lds + mj * Hn);
        const float* row = Wg + ((size_t)mj * NGn + g_raw) * 65;
        float acc = fmaf(row[0], xj, bg[mj * NGn + g_raw]);
        float a0 = 0.f, a1 = 0.f, a2 = 0.f, a3 = 0.f;
#pragma unroll
        for (int k4 = 0; k4 < 16; ++k4) {
            float4 hv = hp[k4];
            a0 = fmaf(row[1 + 4*k4 + 0], hv.x, a0);
            a1 = fmaf(row[1 + 4*k4 + 1], hv.y, a1);
            a2 = fmaf(row[1 + 4*k4 + 2], hv.z, a2);
            a3 = fmaf(row[1 + 4*k4 + 3], hv.w, a3);
        }
        acc = fmaf(dec, (a0 + a1) + (a2 + a3), acc);
        const int base = l & ~3;
        const float gi = __shfl(acc, base + 0, 64);
        const float gf = __shfl(acc, base + 1, 64);
        const float go = __shfl(acc, base + 2, 64);
        const float gc = __shfl(acc, base + 3, 64);
        __syncthreads();
        const float c_new = fmaf(sigm_slow(gf), c_lds[u], sigm_slow(gi) * tanhf(gc));
        if (q == 0) {
            c_lds[u] = c_new;
            h_lds[mj * Hn + u] = sigm_slow(go) * tanhf(c_new);
        }
        __syncthreads();
    }

    float p[NCn];
#pragma unroll
    for (int c = 0; c < NCn; ++c) p[c] = 0.0f;
    for (int i = tid; i < IN_DIM; i += 256) {
        const float fv = (i < Hn) ? c_lds[i] : h_lds[i - Hn];
#pragma unroll
        for (int c = 0; c < NCn; ++c)
            p[c] = fmaf(Wo[(size_t)c * IN_DIM + i], fv, p[c]);
    }
#pragma unroll
    for (int c = 0; c < NCn; ++c) {
        float v = p[c];
#pragma unroll
        for (int off = 32; off > 0; off >>= 1) v += __shfl_down(v, off, 64);
        if (l == 0) red_lds[w * NCn + c] = v;
    }
    __syncthreads();
    if (tid < NCn) {
        logit_lds[tid] = red_lds[tid] + red_lds[NCn + tid] +
                         red_lds[2 * NCn + tid] + red_lds[3 * NCn + tid] + bo[tid];
    }
    __syncthreads();
    if (tid == 0) {
        float mx = logit_lds[0];
        for (int c = 1; c < NCn; ++c) mx = fmaxf(mx, logit_lds[c]);
        float e[NCn], s = 0.0f;
        for (int c = 0; c < NCn; ++c) { e[c] = expf(logit_lds[c] - mx); s += e[c]; }
        const float inv = 1.0f / s;
        for (int c = 0; c < NCn; ++c) out[(size_t)b * NCn + c] = e[c] * inv;
    }
}

extern "C" void kernel_launch(void* const* d_in, const int* in_sizes, int n_in,
                              void* d_out, int out_size, void* d_ws, size_t ws_size,
                              hipStream_t stream)
{
    const float* X      = (const float*)d_in[0];
    const int*   len    = (const int*)  d_in[1];
    const float* Wg     = (const float*)d_in[2];
    const float* bg     = (const float*)d_in[3];
    const float* wdec   = (const float*)d_in[4];
    const float* bdec   = (const float*)d_in[5];
    const float* Wo     = (const float*)d_in[6];
    const float* bo     = (const float*)d_in[7];
    float*       out    = (float*)d_out;

    const size_t gw_bytes  = (size_t)Fn * 2048 * sizeof(f16x8);   // 4,194,304
    const size_t gwb_bytes = (size_t)Fn * 256 * sizeof(f32x2);    // 262,144
    const size_t need      = gw_bytes + gwb_bytes;

    if (ws_size >= need) {
        f16x8* Gw  = (f16x8*)d_ws;
        f32x2* Gwb = (f32x2*)((char*)d_ws + gw_bytes);
        prep_f16<<<Fn, 256, 0, stream>>>(Wg, bg, Gw, Gwb);
        (void)hipFuncSetAttribute((const void*)lstm_pre,
                                  hipFuncAttributeMaxDynamicSharedMemorySize,
                                  LDS_TOTAL);
        lstm_pre<<<Bn, NT, LDS_TOTAL, stream>>>(X, len, Gw, Gwb,
                                                wdec, bdec, Wo, bo, out);
    } else {
        lstm_fallback<<<Bn, 256, 0, stream>>>(X, len, Wg, bg,
                                              wdec, bdec, Wo, bo, out);
    }
}